// Round 4
// baseline (4389.164 us; speedup 1.0000x reference)
//
#include <hip/hip_runtime.h>
#include <hip/hip_bf16.h>

#define B_   2048
#define V_   1024
#define H_   512
#define E_   256
#define L_   32

typedef __attribute__((ext_vector_type(8))) short bf16x8;
typedef __attribute__((ext_vector_type(4))) float f32x4;
typedef __attribute__((ext_vector_type(2))) long i64x2;
typedef unsigned short u16;
typedef unsigned int   u32;
typedef unsigned char  u8;
typedef long long      i64;

__device__ __forceinline__ u16 f2bf(float x) {
    union { float f; u32 u; } v; v.f = x;
    u32 r = v.u + 0x7fffu + ((v.u >> 16) & 1u);   // RNE
    return (u16)(r >> 16);
}
// OCP e4m3fn encode, RNE, flush below 2^-6 (callers pre-scale so this is negligible)
__device__ __forceinline__ u8 f2e4m3(float x) {
    union { float f; u32 u; } v; v.f = x;
    u32 s = (v.u >> 24) & 0x80u;
    u32 a = v.u & 0x7fffffffu;
    if (a < 0x3c800000u) return (u8)s;            // |x| < 2^-6 -> 0
    if (a > 0x43e00000u) a = 0x43e00000u;         // clamp 448
    u32 r = a + 0x000fffffu + ((a >> 20) & 1u);   // RNE to 3-bit mantissa
    if (r > 0x43e00000u) r = 0x43e00000u;
    u32 ex = (r >> 23) - 120u;                    // biased e4m3 exponent (bias 7)
    u32 mn = (r >> 20) & 7u;
    return (u8)(s | (ex << 3) | mn);
}
__device__ __forceinline__ float sig_(float x)  { return 1.f / (1.f + __expf(-x)); }
__device__ __forceinline__ float tanh_(float x) { return 1.f - 2.f / (__expf(2.f * x) + 1.f); }

// -------------------------------------------------------------------------
// Weight layouts (per-wave register-load order):
// w1f (fp8, x64): [ks 24][g 4][wv 16][l 64][jj 2][e 8]
//                 k = ks*32+(l>>4)*8+e,  n = g*512 + wv*32 + jj*16 + (l&15)
//                 -> one dwordx4/lane = both jj fragments of (ks,g) for wave wv
// wof (bf16)    : [half 2][ks 16][m 32][l 64][e 8]
//                 v = half*512+(m>>1)*32+(m&1)*16+(l&15),  m = 2*wv+jj
// wef (fp8, x64): [c 16][wv 16][l 64][s 2][e 8]
//                 k = (2c+s)*32+(l>>4)*8+e,  col = wv*16+(l&15)
// b1 = b_ih + b_hh (fp32)
// -------------------------------------------------------------------------
__global__ void prep(const float* __restrict__ W_ih, const float* __restrict__ W_hh,
                     const float* __restrict__ b_ih, const float* __restrict__ b_hh,
                     const float* __restrict__ W_out, const float* __restrict__ W_emb,
                     u8* __restrict__ w1f, u16* __restrict__ wof, u8* __restrict__ wef,
                     float* __restrict__ b1)
{
    int idx = blockIdx.x * 256 + threadIdx.x;
    if (idx < 1572864) {                       // W1 = [W_ih | W_hh] -> fp8*64
        int e = idx & 7, jj = (idx >> 3) & 1, l = (idx >> 4) & 63,
            wv = (idx >> 10) & 15, g = (idx >> 14) & 3, ks = idx >> 16;
        int k = ks * 32 + ((l >> 4) << 3) + e;
        int n = g * 512 + wv * 32 + jj * 16 + (l & 15);
        float v = (k < E_) ? W_ih[n * E_ + k] : W_hh[n * H_ + (k - E_)];
        w1f[idx] = f2e4m3(v * 64.f);
    } else if (idx < 2097152) {                // W_out -> bf16
        int j = idx - 1572864;
        int e = j & 7, l = (j >> 3) & 63, m = (j >> 9) & 31, ks = (j >> 14) & 15, hf = (j >> 18);
        int k = ks * 32 + ((l >> 4) << 3) + e;
        int v = hf * 512 + ((m >> 1) << 5) + ((m & 1) << 4) + (l & 15);
        wof[j] = f2bf(W_out[v * H_ + k]);
    } else if (idx < 2359296) {                // W_emb -> fp8*64
        int j = idx - 2097152;
        int e = j & 7, s = (j >> 3) & 1, l = (j >> 4) & 63, wv = (j >> 10) & 15, c = j >> 14;
        int k = (2 * c + s) * 32 + ((l >> 4) << 3) + e;
        int ce = wv * 16 + (l & 15);
        wef[j] = f2e4m3(W_emb[ce * V_ + k] * 64.f);
    } else if (idx < 2361344) {
        int j = idx - 2359296;
        b1[j] = b_ih[j] + b_hh[j];
    }
}

// LDS layout (bytes) — A-operands + reductions only; weights never touch LDS
#define AEO   0u        // 16 x 776 fp8: [0,256) e*16, [256,768) h*16
#define HBO   12416u    // 16 x 528 u16 bf16 h (stride 1056 B)
#define XSO   29312u    // 16 x 1040 fp8 xs = exp(z-m)*256
#define RMX   45952u    // 16x16 f32 row-max partials
#define RSM   46976u    // 16x16 f32 row-sum partials
#define LDS_TOTAL 48000

__global__ __launch_bounds__(1024, 4)
void lstm_fused(const float* __restrict__ x, const float* __restrict__ gum,
                const u8* __restrict__ w1f, const u16* __restrict__ wof,
                const u8* __restrict__ wef, const float* __restrict__ b1,
                const float* __restrict__ b_out, const float* __restrict__ b_emb,
                const float* __restrict__ sos, float* __restrict__ out)
{
    __shared__ __align__(16) char smem[LDS_TOTAL];

    const u32 tid = threadIdx.x;
    const u32 w   = tid >> 6;        // wave 0..15
    const u32 l   = tid & 63u;
    const u32 q   = l >> 4;
    const u32 col = l & 15u;
    const int r0  = blockIdx.x << 4;

    const u32 q8  = q << 3;
    const u32 colB776  = col * 776u;
    const u32 colB1040 = col * 1040u;
    const u32 colB1056 = col * 1056u;

    // per-wave/lane weight base pointers
    const char* w1base = (const char*)w1f + (w << 10) + (l << 4);  // + ks*65536 + g*16384
    const char* wobase = (const char*)wof + (w << 11) + (l << 4);  // + chunk*32768 (+1024 for jj=1)
    const char* webase = (const char*)wef + (w << 10) + (l << 4);  // + c*16384

    // EOS row
    for (u32 i = tid; i < 16 * V_; i += 1024) {
        u32 b = i >> 10, v = i & (V_ - 1);
        out[((size_t)(r0 + b) * 33 + 32) * V_ + v] = (v == 0) ? 1.f : 0.f;
    }
    // e0 = sos*16 (fp8), h0 = x*16 (fp8)
    for (u32 i = tid; i < 16 * E_; i += 1024) {
        u32 b = i >> 8, k = i & (E_ - 1);
        *(u8*)(smem + AEO + b * 776u + k) = f2e4m3(sos[k] * 16.f);
    }
    for (u32 i = tid; i < 16 * H_; i += 1024) {
        u32 b = i >> 9, k = i & (H_ - 1);
        *(u8*)(smem + AEO + b * 776u + 256u + k) = f2e4m3(x[(r0 + b) * H_ + k] * 16.f);
    }

    // hoisted biases
    float bia[2], bfa[2], bga[2], boa[2];
    #pragma unroll
    for (int jj = 0; jj < 2; ++jj) {
        int j = (w << 5) + (jj << 4) + col;
        bia[jj] = b1[j];           bfa[jj] = b1[H_ + j];
        bga[jj] = b1[2 * H_ + j];  boa[jj] = b1[3 * H_ + j];
    }
    float bov[2][2];
    #pragma unroll
    for (int hf = 0; hf < 2; ++hf)
        #pragma unroll
        for (int jj = 0; jj < 2; ++jj)
            bov[hf][jj] = b_out[hf * 512 + (w << 5) + (jj << 4) + col];
    const float bem16 = b_emb[(w << 4) + col] * 16.f;

    float creg[2][4];
    #pragma unroll
    for (int jj = 0; jj < 2; ++jj)
        #pragma unroll
        for (int r = 0; r < 4; ++r) creg[jj][r] = 0.f;

    __syncthreads();

    const f32x4 fz = {0.f, 0.f, 0.f, 0.f};
    const float S1 = 1.f / 1024.f;            // 1/(A_SC*W_SC) = 1/(16*64)

    #pragma unroll 1
    for (int t = 0; t < L_; ++t) {
        // =============== phase A: gates (fp8 x fp8), reg-staged depth 3 ===============
        f32x4 acc[4][2];
        #pragma unroll
        for (int g = 0; g < 4; ++g) { acc[g][0] = fz; acc[g][1] = fz; }

        i64x2 sA[3][4];
#define LDA(KS, BUF) { const char* _p = w1base + (KS) * 65536; \
        sA[BUF][0] = *(const i64x2*)(_p); \
        sA[BUF][1] = *(const i64x2*)(_p + 16384); \
        sA[BUF][2] = *(const i64x2*)(_p + 32768); \
        sA[BUF][3] = *(const i64x2*)(_p + 49152); }
        LDA(0, 0); LDA(1, 1); LDA(2, 2);
        #pragma unroll
        for (int ks = 0; ks < 24; ++ks) {
            i64 a8 = *(const i64*)(smem + AEO + colB776 + (ks << 5) + q8);
            const int bfi = ks % 3;
            #pragma unroll
            for (int g = 0; g < 4; ++g) {
                acc[g][0] = __builtin_amdgcn_mfma_f32_16x16x32_fp8_fp8(a8, sA[bfi][g][0], acc[g][0], 0, 0, 0);
                acc[g][1] = __builtin_amdgcn_mfma_f32_16x16x32_fp8_fp8(a8, sA[bfi][g][1], acc[g][1], 0, 0, 0);
            }
            if (ks < 21) { LDA(ks + 3, bfi); }
        }
#undef LDA
        __syncthreads();            // all AEO reads done before h overwrite

        #pragma unroll
        for (int jj = 0; jj < 2; ++jj) {
            int j = (w << 5) + (jj << 4) + col;
            #pragma unroll
            for (int r = 0; r < 4; ++r) {
                float gi = sig_(acc[0][jj][r] * S1 + bia[jj]);
                float gf = sig_(acc[1][jj][r] * S1 + bfa[jj]);
                float gg = tanh_(acc[2][jj][r] * S1 + bga[jj]);
                float go = sig_(acc[3][jj][r] * S1 + boa[jj]);
                float c  = gf * creg[jj][r] + gi * gg;
                creg[jj][r] = c;
                float h = go * tanh_(c);
                u32 b = (q << 2) + r;
                *(u8*)(smem + AEO + b * 776u + 256u + (u32)j) = f2e4m3(h * 16.f);
                *(u16*)(smem + HBO + b * 1056u + ((u32)j << 1)) = f2bf(h);
            }
        }
        __syncthreads();            // h complete

        // =============== phase B: logits (bf16, reg-staged depth 4) + softmax ===============
        const float* gt = gum + (size_t)t * (B_ * V_) + (size_t)r0 * V_;
        float gr[2][2][4];
        #pragma unroll
        for (int hf = 0; hf < 2; ++hf)
            #pragma unroll
            for (int jj = 0; jj < 2; ++jj) {
                int v = hf * 512 + (w << 5) + (jj << 4) + col;
                #pragma unroll
                for (int r = 0; r < 4; ++r)
                    gr[hf][jj][r] = gt[((q << 2) + r) * V_ + v];
            }

        f32x4 accB[2][2];
        accB[0][0] = fz; accB[0][1] = fz; accB[1][0] = fz; accB[1][1] = fz;

        bf16x8 sB[4][2];
#define LDB(HK, BUF) { const char* _p = wobase + (size_t)(HK) * 32768; \
        sB[BUF][0] = *(const bf16x8*)(_p); \
        sB[BUF][1] = *(const bf16x8*)(_p + 1024); }
        LDB(0, 0); LDB(1, 1); LDB(2, 2); LDB(3, 3);
        #pragma unroll
        for (int hk = 0; hk < 32; ++hk) {
            int ksl = hk & 15;
            int hf  = hk >> 4;
            const int bfi = hk & 3;
            bf16x8 af = *(const bf16x8*)(smem + HBO + colB1056 + (ksl << 6) + (q << 4));
            accB[hf][0] = __builtin_amdgcn_mfma_f32_16x16x32_bf16(af, sB[bfi][0], accB[hf][0], 0, 0, 0);
            accB[hf][1] = __builtin_amdgcn_mfma_f32_16x16x32_bf16(af, sB[bfi][1], accB[hf][1], 0, 0, 0);
            if (hk < 28) { LDB(hk + 4, bfi); }
        }
#undef LDB

        // z, row-max, exp, row-sum
        float z[2][2][4];
        float mx[4];
        #pragma unroll
        for (int r = 0; r < 4; ++r) mx[r] = -1e30f;
        #pragma unroll
        for (int hf = 0; hf < 2; ++hf)
            #pragma unroll
            for (int jj = 0; jj < 2; ++jj)
                #pragma unroll
                for (int r = 0; r < 4; ++r) {
                    float zz = accB[hf][jj][r] + bov[hf][jj] + gr[hf][jj][r];
                    z[hf][jj][r] = zz;
                    mx[r] = fmaxf(mx[r], zz);
                }
        #pragma unroll
        for (int m = 1; m < 16; m <<= 1)
            #pragma unroll
            for (int r = 0; r < 4; ++r) mx[r] = fmaxf(mx[r], __shfl_xor(mx[r], m, 64));
        if (col == 0) {
            #pragma unroll
            for (int r = 0; r < 4; ++r)
                *(float*)(smem + RMX + (((q << 2) + r) * 16u + w) * 4u) = mx[r];
        }
        __syncthreads();
        float m_[4];
        #pragma unroll
        for (int r = 0; r < 4; ++r) {
            float mm = -1e30f;
            #pragma unroll
            for (int ww = 0; ww < 16; ++ww)
                mm = fmaxf(mm, *(const float*)(smem + RMX + (((q << 2) + r) * 16u + ww) * 4u));
            m_[r] = mm;
        }
        float eb[2][2][4];
        float ps[4] = {0.f, 0.f, 0.f, 0.f};
        #pragma unroll
        for (int hf = 0; hf < 2; ++hf)
            #pragma unroll
            for (int jj = 0; jj < 2; ++jj)
                #pragma unroll
                for (int r = 0; r < 4; ++r) {
                    float Ee = __expf(z[hf][jj][r] - m_[r]);
                    eb[hf][jj][r] = Ee;
                    ps[r] += Ee;
                }
        #pragma unroll
        for (int m = 1; m < 16; m <<= 1)
            #pragma unroll
            for (int r = 0; r < 4; ++r) ps[r] += __shfl_xor(ps[r], m, 64);
        if (col == 0) {
            #pragma unroll
            for (int r = 0; r < 4; ++r)
                *(float*)(smem + RSM + (((q << 2) + r) * 16u + w) * 4u) = ps[r];
        }
        // stage xs = exp(z-m)*256 as fp8 (usable before sum known)
        #pragma unroll
        for (int hf = 0; hf < 2; ++hf)
            #pragma unroll
            for (int jj = 0; jj < 2; ++jj) {
                u32 v = (u32)(hf * 512 + (w << 5) + (jj << 4) + col);
                #pragma unroll
                for (int r = 0; r < 4; ++r)
                    *(u8*)(smem + XSO + ((q << 2) + r) * 1040u + v) = f2e4m3(eb[hf][jj][r] * 256.f);
            }
        __syncthreads();
        float invs[4];
        #pragma unroll
        for (int r = 0; r < 4; ++r) {
            float s = 0.f;
            #pragma unroll
            for (int ww = 0; ww < 16; ++ww)
                s += *(const float*)(smem + RSM + (((q << 2) + r) * 16u + ww) * 4u);
            invs[r] = 1.f / s;
        }
        // normalized softmax out (fp32)
        #pragma unroll
        for (int hf = 0; hf < 2; ++hf)
            #pragma unroll
            for (int jj = 0; jj < 2; ++jj) {
                int v = hf * 512 + (w << 5) + (jj << 4) + col;
                #pragma unroll
                for (int r = 0; r < 4; ++r) {
                    int b = (q << 2) + r;
                    out[((size_t)(r0 + b) * 33 + t) * V_ + v] = eb[hf][jj][r] * invs[r];
                }
            }

        // =============== phase C: e_new (fp8 x fp8), reg-staged depth 3 ===============
        f32x4 accC = fz;
        i64x2 sC[3];
#define LDC(C, BUF) sC[BUF] = *(const i64x2*)(webase + (C) * 16384);
        LDC(0, 0); LDC(1, 1); LDC(2, 2);
        #pragma unroll
        for (int c2 = 0; c2 < 16; ++c2) {
            const int bfi = c2 % 3;
            i64 a0 = *(const i64*)(smem + XSO + colB1040 + ((u32)(2 * c2) << 5) + q8);
            i64 a1 = *(const i64*)(smem + XSO + colB1040 + ((u32)(2 * c2 + 1) << 5) + q8);
            accC = __builtin_amdgcn_mfma_f32_16x16x32_fp8_fp8(a0, sC[bfi][0], accC, 0, 0, 0);
            accC = __builtin_amdgcn_mfma_f32_16x16x32_fp8_fp8(a1, sC[bfi][1], accC, 0, 0, 0);
            if (c2 < 13) { LDC(c2 + 3, bfi); }
        }
#undef LDC

        {   // e = accC*invs/(256*64) + b_emb ; store e*16 as fp8
            u32 ce = (w << 4) + col;
            #pragma unroll
            for (int r = 0; r < 4; ++r) {
                float e_ = accC[r] * invs[r] * (16.f / 16384.f) + bem16;
                *(u8*)(smem + AEO + ((q << 2) + r) * 776u + ce) = f2e4m3(e_);
            }
        }
        __syncthreads();            // e complete before next step's phase A
    }
}

extern "C" void kernel_launch(void* const* d_in, const int* in_sizes, int n_in,
                              void* d_out, int out_size, void* d_ws, size_t ws_size,
                              hipStream_t stream) {
    const float* x     = (const float*)d_in[0];
    const float* gum   = (const float*)d_in[1];
    const float* W_ih  = (const float*)d_in[2];
    const float* W_hh  = (const float*)d_in[3];
    const float* b_ih  = (const float*)d_in[4];
    const float* b_hh  = (const float*)d_in[5];
    const float* W_out = (const float*)d_in[6];
    const float* b_out = (const float*)d_in[7];
    const float* W_emb = (const float*)d_in[8];
    const float* b_emb = (const float*)d_in[9];
    const float* sos   = (const float*)d_in[10];
    float* out = (float*)d_out;

    char* ws = (char*)d_ws;
    u8*    w1f = (u8*)(ws);                    // 1,572,864 B (fp8)
    u16*   wof = (u16*)(ws + 1572864);         // 1,048,576 B (bf16)
    u8*    wef = (u8*)(ws + 2621440);          //   262,144 B (fp8)
    float* b1  = (float*)(ws + 2883584);       //     8,192 B

    prep<<<9224, 256, 0, stream>>>(W_ih, W_hh, b_ih, b_hh, W_out, W_emb,
                                   w1f, wof, wef, b1);
    lstm_fused<<<128, 1024, 0, stream>>>(x, gum, w1f, wof, wef, b1,
                                         b_out, b_emb, sos, out);
}

// Round 5
// 3532.450 us; speedup vs baseline: 1.2425x; 1.2425x over previous
//
#include <hip/hip_runtime.h>
#include <hip/hip_bf16.h>

#define B_   2048
#define V_   1024
#define H_   512
#define E_   256
#define L_   32

typedef __attribute__((ext_vector_type(8))) short bf16x8;
typedef __attribute__((ext_vector_type(4))) float f32x4;
typedef __attribute__((ext_vector_type(2))) long i64x2;
typedef unsigned short u16;
typedef unsigned int   u32;
typedef unsigned char  u8;
typedef long long      i64;

// OCP e4m3fn encode, RNE, flush below 2^-6 (callers pre-scale so this is negligible)
__device__ __forceinline__ u8 f2e4m3(float x) {
    union { float f; u32 u; } v; v.f = x;
    u32 s = (v.u >> 24) & 0x80u;
    u32 a = v.u & 0x7fffffffu;
    if (a < 0x3c800000u) return (u8)s;            // |x| < 2^-6 -> 0
    if (a > 0x43e00000u) a = 0x43e00000u;         // clamp 448
    u32 r = a + 0x000fffffu + ((a >> 20) & 1u);   // RNE to 3-bit mantissa
    if (r > 0x43e00000u) r = 0x43e00000u;
    u32 ex = (r >> 23) - 120u;                    // biased e4m3 exponent (bias 7)
    u32 mn = (r >> 20) & 7u;
    return (u8)(s | (ex << 3) | mn);
}
__device__ __forceinline__ float sig_(float x)  { return 1.f / (1.f + __expf(-x)); }
__device__ __forceinline__ float tanh_(float x) { return 1.f - 2.f / (__expf(2.f * x) + 1.f); }

// -------------------------------------------------------------------------
// Weight layouts (per-wave register-load order), all fp8 e4m3 scaled x64:
// w1f: [ks 24][g 4][wv 16][l 64][jj 2][e 8]
//      k = ks*32+(l>>4)*8+e,  n = g*512 + wv*32 + jj*16 + (l&15)
//      -> one dwordx4/lane = both jj fragments of (ks,g) for wave wv
// wof: [hf 2][ks 16][wv 16][l 64][jj 2][e 8]
//      k = ks*32+(l>>4)*8+e,  v = hf*512 + wv*32 + jj*16 + (l&15)
// wef: [c 16][wv 16][l 64][s 2][e 8]
//      k = (2c+s)*32+(l>>4)*8+e,  col = wv*16+(l&15)
// b1 = b_ih + b_hh (fp32)
// -------------------------------------------------------------------------
__global__ void prep(const float* __restrict__ W_ih, const float* __restrict__ W_hh,
                     const float* __restrict__ b_ih, const float* __restrict__ b_hh,
                     const float* __restrict__ W_out, const float* __restrict__ W_emb,
                     u8* __restrict__ w1f, u8* __restrict__ wof, u8* __restrict__ wef,
                     float* __restrict__ b1)
{
    int idx = blockIdx.x * 256 + threadIdx.x;
    if (idx < 1572864) {                       // W1 = [W_ih | W_hh] -> fp8*64
        int e = idx & 7, jj = (idx >> 3) & 1, l = (idx >> 4) & 63,
            wv = (idx >> 10) & 15, g = (idx >> 14) & 3, ks = idx >> 16;
        int k = ks * 32 + ((l >> 4) << 3) + e;
        int n = g * 512 + wv * 32 + jj * 16 + (l & 15);
        float v = (k < E_) ? W_ih[n * E_ + k] : W_hh[n * H_ + (k - E_)];
        w1f[idx] = f2e4m3(v * 64.f);
    } else if (idx < 2097152) {                // W_out -> fp8*64
        int j = idx - 1572864;
        int e = j & 7, jj = (j >> 3) & 1, l = (j >> 4) & 63,
            wv = (j >> 10) & 15, ks = (j >> 14) & 15, hf = (j >> 18) & 1;
        int k = ks * 32 + ((l >> 4) << 3) + e;
        int v = hf * 512 + wv * 32 + jj * 16 + (l & 15);
        wof[j] = f2e4m3(W_out[v * H_ + k] * 64.f);
    } else if (idx < 2359296) {                // W_emb -> fp8*64
        int j = idx - 2097152;
        int e = j & 7, s = (j >> 3) & 1, l = (j >> 4) & 63, wv = (j >> 10) & 15, c = j >> 14;
        int k = (2 * c + s) * 32 + ((l >> 4) << 3) + e;
        int ce = wv * 16 + (l & 15);
        wef[j] = f2e4m3(W_emb[ce * V_ + k] * 64.f);
    } else if (idx < 2361344) {
        int j = idx - 2359296;
        b1[j] = b_ih[j] + b_hh[j];
    }
}

// LDS layout (bytes) — activations + reductions only; weights never touch LDS
#define AEO   0u        // 16 x 776 fp8: [0,256) e*16, [256,768) h*16
#define XSO   12416u    // 16 x 1040 fp8 xs = exp(z-m)*256
#define RMX   29056u    // 16x16 f32 row-max partials
#define RSM   30080u    // 16x16 f32 row-sum partials
#define LDS_TOTAL 31104

__global__ __launch_bounds__(1024)
__attribute__((amdgpu_waves_per_eu(4, 4)))
void lstm_fused(const float* __restrict__ x, const float* __restrict__ gum,
                const u8* __restrict__ w1f, const u8* __restrict__ wof,
                const u8* __restrict__ wef, const float* __restrict__ b1,
                const float* __restrict__ b_out, const float* __restrict__ b_emb,
                const float* __restrict__ sos, float* __restrict__ out)
{
    __shared__ __align__(16) char smem[LDS_TOTAL];

    const u32 tid = threadIdx.x;
    const u32 w   = tid >> 6;        // wave 0..15
    const u32 l   = tid & 63u;
    const u32 q   = l >> 4;
    const u32 col = l & 15u;
    const int r0  = blockIdx.x << 4;

    const u32 q8  = q << 3;
    const u32 colB776  = col * 776u;
    const u32 colB1040 = col * 1040u;

    // per-wave/lane weight base pointers
    const char* w1base = (const char*)w1f + (w << 10) + (l << 4);  // + ks*65536 + g*16384
    const char* wobase = (const char*)wof + (w << 10) + (l << 4);  // + c*16384
    const char* webase = (const char*)wef + (w << 10) + (l << 4);  // + c*16384

    // EOS row (nontemporal: pure stream)
    for (u32 i = tid; i < 16 * V_; i += 1024) {
        u32 b = i >> 10, v = i & (V_ - 1);
        __builtin_nontemporal_store((v == 0) ? 1.f : 0.f,
                                    &out[((size_t)(r0 + b) * 33 + 32) * V_ + v]);
    }
    // e0 = sos*16 (fp8), h0 = x*16 (fp8)
    for (u32 i = tid; i < 16 * E_; i += 1024) {
        u32 b = i >> 8, k = i & (E_ - 1);
        *(u8*)(smem + AEO + b * 776u + k) = f2e4m3(sos[k] * 16.f);
    }
    for (u32 i = tid; i < 16 * H_; i += 1024) {
        u32 b = i >> 9, k = i & (H_ - 1);
        *(u8*)(smem + AEO + b * 776u + 256u + k) = f2e4m3(x[(r0 + b) * H_ + k] * 16.f);
    }

    // hoisted biases
    float bia[2], bfa[2], bga[2], boa[2];
    #pragma unroll
    for (int jj = 0; jj < 2; ++jj) {
        int j = (w << 5) + (jj << 4) + col;
        bia[jj] = b1[j];           bfa[jj] = b1[H_ + j];
        bga[jj] = b1[2 * H_ + j];  boa[jj] = b1[3 * H_ + j];
    }
    float bov[2][2];
    #pragma unroll
    for (int hf = 0; hf < 2; ++hf)
        #pragma unroll
        for (int jj = 0; jj < 2; ++jj)
            bov[hf][jj] = b_out[hf * 512 + (w << 5) + (jj << 4) + col];
    const float bem16 = b_emb[(w << 4) + col] * 16.f;

    float creg[2][4];
    #pragma unroll
    for (int jj = 0; jj < 2; ++jj)
        #pragma unroll
        for (int r = 0; r < 4; ++r) creg[jj][r] = 0.f;

    __syncthreads();

    const f32x4 fz = {0.f, 0.f, 0.f, 0.f};
    const float S1 = 1.f / 1024.f;            // 1/(A_SC*W_SC) = 1/(16*64)

    #pragma unroll 1
    for (int t = 0; t < L_; ++t) {
        // =============== phase A: gates (fp8 x fp8), reg ring depth 3 ===============
        f32x4 acc[4][2];
        #pragma unroll
        for (int g = 0; g < 4; ++g) { acc[g][0] = fz; acc[g][1] = fz; }

        i64x2 sA[3][4];
#define LDA(KS, BUF) { const char* _p = w1base + (KS) * 65536; \
        sA[BUF][0] = *(const i64x2*)(_p); \
        sA[BUF][1] = *(const i64x2*)(_p + 16384); \
        sA[BUF][2] = *(const i64x2*)(_p + 32768); \
        sA[BUF][3] = *(const i64x2*)(_p + 49152); }
        LDA(0, 0); LDA(1, 1); LDA(2, 2);
        #pragma unroll
        for (int ks = 0; ks < 24; ++ks) {
            i64 a8 = *(const i64*)(smem + AEO + colB776 + ((u32)ks << 5) + q8);
            const int bfi = ks % 3;
            #pragma unroll
            for (int g = 0; g < 4; ++g) {
                acc[g][0] = __builtin_amdgcn_mfma_f32_16x16x32_fp8_fp8(a8, sA[bfi][g][0], acc[g][0], 0, 0, 0);
                acc[g][1] = __builtin_amdgcn_mfma_f32_16x16x32_fp8_fp8(a8, sA[bfi][g][1], acc[g][1], 0, 0, 0);
            }
            if (ks < 21) { LDA(ks + 3, bfi); }
        }
#undef LDA
        __syncthreads();            // all AEO reads done before h overwrite

        #pragma unroll
        for (int jj = 0; jj < 2; ++jj) {
            int j = (w << 5) + (jj << 4) + col;
            #pragma unroll
            for (int r = 0; r < 4; ++r) {
                float gi = sig_(acc[0][jj][r] * S1 + bia[jj]);
                float gf = sig_(acc[1][jj][r] * S1 + bfa[jj]);
                float gg = tanh_(acc[2][jj][r] * S1 + bga[jj]);
                float go = sig_(acc[3][jj][r] * S1 + boa[jj]);
                float c  = gf * creg[jj][r] + gi * gg;
                creg[jj][r] = c;
                float h = go * tanh_(c);
                u32 b = (q << 2) + r;
                *(u8*)(smem + AEO + b * 776u + 256u + (u32)j) = f2e4m3(h * 16.f);
            }
        }
        __syncthreads();            // h complete

        // =============== phase B: logits (fp8 x fp8, ring depth 4) + softmax ===============
        const float* gt = gum + (size_t)t * (B_ * V_) + (size_t)r0 * V_;
        float gr[2][2][4];
        #pragma unroll
        for (int hf = 0; hf < 2; ++hf)
            #pragma unroll
            for (int jj = 0; jj < 2; ++jj) {
                int v = hf * 512 + (w << 5) + (jj << 4) + col;
                #pragma unroll
                for (int r = 0; r < 4; ++r)
                    gr[hf][jj][r] = __builtin_nontemporal_load(&gt[((q << 2) + r) * V_ + v]);
            }

        f32x4 accB[2][2];
        accB[0][0] = fz; accB[0][1] = fz; accB[1][0] = fz; accB[1][1] = fz;

        i64x2 sB[4];
#define LDB(HK, BUF) sB[BUF] = *(const i64x2*)(wobase + (size_t)(HK) * 16384);
        LDB(0, 0); LDB(1, 1); LDB(2, 2); LDB(3, 3);
        #pragma unroll
        for (int hk = 0; hk < 32; ++hk) {
            const int ksl = hk & 15;
            const int hf  = hk >> 4;
            const int bfi = hk & 3;
            i64 a8 = *(const i64*)(smem + AEO + colB776 + 256u + ((u32)ksl << 5) + q8);
            accB[hf][0] = __builtin_amdgcn_mfma_f32_16x16x32_fp8_fp8(a8, sB[bfi][0], accB[hf][0], 0, 0, 0);
            accB[hf][1] = __builtin_amdgcn_mfma_f32_16x16x32_fp8_fp8(a8, sB[bfi][1], accB[hf][1], 0, 0, 0);
            if (hk < 28) { LDB(hk + 4, bfi); }
        }
#undef LDB

        // z, row-max, exp, row-sum
        float z[2][2][4];
        float mx[4];
        #pragma unroll
        for (int r = 0; r < 4; ++r) mx[r] = -1e30f;
        #pragma unroll
        for (int hf = 0; hf < 2; ++hf)
            #pragma unroll
            for (int jj = 0; jj < 2; ++jj)
                #pragma unroll
                for (int r = 0; r < 4; ++r) {
                    float zz = accB[hf][jj][r] * S1 + bov[hf][jj] + gr[hf][jj][r];
                    z[hf][jj][r] = zz;
                    mx[r] = fmaxf(mx[r], zz);
                }
        #pragma unroll
        for (int m = 1; m < 16; m <<= 1)
            #pragma unroll
            for (int r = 0; r < 4; ++r) mx[r] = fmaxf(mx[r], __shfl_xor(mx[r], m, 64));
        if (col == 0) {
            #pragma unroll
            for (int r = 0; r < 4; ++r)
                *(float*)(smem + RMX + (((q << 2) + r) * 16u + w) * 4u) = mx[r];
        }
        __syncthreads();
        float m_[4];
        #pragma unroll
        for (int r = 0; r < 4; ++r) {
            float mm = -1e30f;
            #pragma unroll
            for (int ww = 0; ww < 16; ++ww)
                mm = fmaxf(mm, *(const float*)(smem + RMX + (((q << 2) + r) * 16u + ww) * 4u));
            m_[r] = mm;
        }
        float eb[2][2][4];
        float ps[4] = {0.f, 0.f, 0.f, 0.f};
        #pragma unroll
        for (int hf = 0; hf < 2; ++hf)
            #pragma unroll
            for (int jj = 0; jj < 2; ++jj)
                #pragma unroll
                for (int r = 0; r < 4; ++r) {
                    float Ee = __expf(z[hf][jj][r] - m_[r]);
                    eb[hf][jj][r] = Ee;
                    ps[r] += Ee;
                }
        #pragma unroll
        for (int m = 1; m < 16; m <<= 1)
            #pragma unroll
            for (int r = 0; r < 4; ++r) ps[r] += __shfl_xor(ps[r], m, 64);
        if (col == 0) {
            #pragma unroll
            for (int r = 0; r < 4; ++r)
                *(float*)(smem + RSM + (((q << 2) + r) * 16u + w) * 4u) = ps[r];
        }
        // stage xs = exp(z-m)*256 as fp8 (usable before sum known)
        #pragma unroll
        for (int hf = 0; hf < 2; ++hf)
            #pragma unroll
            for (int jj = 0; jj < 2; ++jj) {
                u32 v = (u32)(hf * 512 + (w << 5) + (jj << 4) + col);
                #pragma unroll
                for (int r = 0; r < 4; ++r)
                    *(u8*)(smem + XSO + ((q << 2) + r) * 1040u + v) = f2e4m3(eb[hf][jj][r] * 256.f);
            }
        __syncthreads();
        float invs[4];
        #pragma unroll
        for (int r = 0; r < 4; ++r) {
            float s = 0.f;
            #pragma unroll
            for (int ww = 0; ww < 16; ++ww)
                s += *(const float*)(smem + RSM + (((q << 2) + r) * 16u + ww) * 4u);
            invs[r] = 1.f / s;
        }
        // normalized softmax out (fp32, nontemporal stream)
        #pragma unroll
        for (int hf = 0; hf < 2; ++hf)
            #pragma unroll
            for (int jj = 0; jj < 2; ++jj) {
                int v = hf * 512 + (w << 5) + (jj << 4) + col;
                #pragma unroll
                for (int r = 0; r < 4; ++r) {
                    int b = (q << 2) + r;
                    __builtin_nontemporal_store(eb[hf][jj][r] * invs[r],
                        &out[((size_t)(r0 + b) * 33 + t) * V_ + v]);
                }
            }

        // =============== phase C: e_new (fp8 x fp8), reg ring depth 3 ===============
        f32x4 accC = fz;
        i64x2 sC[3];
#define LDC(C, BUF) sC[BUF] = *(const i64x2*)(webase + (C) * 16384);
        LDC(0, 0); LDC(1, 1); LDC(2, 2);
        #pragma unroll
        for (int c2 = 0; c2 < 16; ++c2) {
            const int bfi = c2 % 3;
            i64 a0 = *(const i64*)(smem + XSO + colB1040 + ((u32)(2 * c2) << 5) + q8);
            i64 a1 = *(const i64*)(smem + XSO + colB1040 + ((u32)(2 * c2 + 1) << 5) + q8);
            accC = __builtin_amdgcn_mfma_f32_16x16x32_fp8_fp8(a0, sC[bfi][0], accC, 0, 0, 0);
            accC = __builtin_amdgcn_mfma_f32_16x16x32_fp8_fp8(a1, sC[bfi][1], accC, 0, 0, 0);
            if (c2 < 13) { LDC(c2 + 3, bfi); }
        }
#undef LDC

        {   // e = accC*invs/(256*64) + b_emb ; store e*16 as fp8
            u32 ce = (w << 4) + col;
            #pragma unroll
            for (int r = 0; r < 4; ++r) {
                float e_ = accC[r] * invs[r] * (16.f / 16384.f) + bem16;
                *(u8*)(smem + AEO + ((q << 2) + r) * 776u + ce) = f2e4m3(e_);
            }
        }
        __syncthreads();            // e complete before next step's phase A
    }
}

extern "C" void kernel_launch(void* const* d_in, const int* in_sizes, int n_in,
                              void* d_out, int out_size, void* d_ws, size_t ws_size,
                              hipStream_t stream) {
    const float* x     = (const float*)d_in[0];
    const float* gum   = (const float*)d_in[1];
    const float* W_ih  = (const float*)d_in[2];
    const float* W_hh  = (const float*)d_in[3];
    const float* b_ih  = (const float*)d_in[4];
    const float* b_hh  = (const float*)d_in[5];
    const float* W_out = (const float*)d_in[6];
    const float* b_out = (const float*)d_in[7];
    const float* W_emb = (const float*)d_in[8];
    const float* b_emb = (const float*)d_in[9];
    const float* sos   = (const float*)d_in[10];
    float* out = (float*)d_out;

    char* ws = (char*)d_ws;
    u8*    w1f = (u8*)(ws);                    // 1,572,864 B (fp8)
    u8*    wof = (u8*)(ws + 1572864);          //   524,288 B (fp8)
    u8*    wef = (u8*)(ws + 2097152);          //   262,144 B (fp8)
    float* b1  = (float*)(ws + 2359296);       //     8,192 B

    prep<<<9224, 256, 0, stream>>>(W_ih, W_hh, b_ih, b_hh, W_out, W_emb,
                                   w1f, wof, wef, b1);
    lstm_fused<<<128, 1024, 0, stream>>>(x, gum, w1f, wof, wef, b1,
                                         b_out, b_emb, sos, out);
}

// Round 6
// 1219.628 us; speedup vs baseline: 3.5988x; 2.8963x over previous
//
#include <hip/hip_runtime.h>
#include <hip/hip_bf16.h>

#define B_   2048
#define V_   1024
#define H_   512
#define E_   256
#define L_   32

typedef __attribute__((ext_vector_type(4))) float f32x4;
typedef unsigned short u16;
typedef unsigned int   u32;
typedef unsigned char  u8;
typedef long long      i64;

// OCP e4m3fn encode, RNE, flush below 2^-6 (callers pre-scale so this is negligible)
__device__ __forceinline__ u8 f2e4m3(float x) {
    union { float f; u32 u; } v; v.f = x;
    u32 s = (v.u >> 24) & 0x80u;
    u32 a = v.u & 0x7fffffffu;
    if (a < 0x3c800000u) return (u8)s;            // |x| < 2^-6 -> 0
    if (a > 0x43e00000u) a = 0x43e00000u;         // clamp 448
    u32 r = a + 0x000fffffu + ((a >> 20) & 1u);   // RNE to 3-bit mantissa
    if (r > 0x43e00000u) r = 0x43e00000u;
    u32 ex = (r >> 23) - 120u;
    u32 mn = (r >> 20) & 7u;
    return (u8)(s | (ex << 3) | mn);
}
__device__ __forceinline__ float sig_(float x)  { return 1.f / (1.f + __expf(-x)); }
__device__ __forceinline__ float tanh_(float x) { return 1.f - 2.f / (__expf(2.f * x) + 1.f); }

// -------------------------------------------------------------------------
// Weight layouts (chunked for 8-wave LDS ring; chunk = 16 KB = 8 waves x 2 KB),
// all fp8 e4m3 scaled x64. Inside a wave's 2 KB: [frag][l 64][e 8], frag=512B.
// w1f: [ks 24][g 4][wv 8][jj 4][l 64][e 8]
//      k = ks*32+(l>>4)*8+e,  n = g*512 + wv*64 + jj*16 + (l&15)
// wof: [ks 16][hf 2][wv 8][jj 4][l 64][e 8]
//      k = ks*32+(l>>4)*8+e,  v = wv*128 + hf*64 + jj*16 + (l&15)
// wef: [ksp 16][wv 8][s 2][jj 2][l 64][e 8]
//      k = (2*ksp+s)*32+(l>>4)*8+e,  col = wv*32 + jj*16 + (l&15)
// b1 = b_ih + b_hh (fp32)
// -------------------------------------------------------------------------
__global__ void prep(const float* __restrict__ W_ih, const float* __restrict__ W_hh,
                     const float* __restrict__ b_ih, const float* __restrict__ b_hh,
                     const float* __restrict__ W_out, const float* __restrict__ W_emb,
                     u8* __restrict__ w1f, u8* __restrict__ wof, u8* __restrict__ wef,
                     float* __restrict__ b1)
{
    int idx = blockIdx.x * 256 + threadIdx.x;
    if (idx < 1572864) {                       // W1 = [W_ih | W_hh] -> fp8*64
        int e = idx & 7, l = (idx >> 3) & 63, jj = (idx >> 9) & 3, wv = (idx >> 11) & 7,
            g = (idx >> 14) & 3, ks = idx >> 16;
        int k = ks * 32 + ((l >> 4) << 3) + e;
        int n = g * 512 + wv * 64 + jj * 16 + (l & 15);
        float v = (k < E_) ? W_ih[n * E_ + k] : W_hh[n * H_ + (k - E_)];
        w1f[idx] = f2e4m3(v * 64.f);
    } else if (idx < 2097152) {                // W_out -> fp8*64
        int j = idx - 1572864;
        int e = j & 7, l = (j >> 3) & 63, jj = (j >> 9) & 3, wv = (j >> 11) & 7,
            hf = (j >> 14) & 1, ks = j >> 15;
        int k = ks * 32 + ((l >> 4) << 3) + e;
        int v = wv * 128 + hf * 64 + jj * 16 + (l & 15);
        wof[j] = f2e4m3(W_out[v * H_ + k] * 64.f);
    } else if (idx < 2359296) {                // W_emb -> fp8*64
        int j = idx - 2097152;
        int e = j & 7, l = (j >> 3) & 63, jj = (j >> 9) & 1, s = (j >> 10) & 1,
            wv = (j >> 11) & 7, ksp = j >> 14;
        int k = (2 * ksp + s) * 32 + ((l >> 4) << 3) + e;
        int ce = wv * 32 + jj * 16 + (l & 15);
        wef[j] = f2e4m3(W_emb[ce * V_ + k] * 64.f);
    } else if (idx < 2361344) {
        int j = idx - 2359296;
        b1[j] = b_ih[j] + b_hh[j];
    }
}

// LDS layout (bytes)
#define STG   0u        // ring: 8 slots x 16384 (8 waves x 2 KB each)
#define AEO   131072u   // 16 x 776 fp8: [0,256) e*16, [256,768) h*16
#define XSO   143488u   // 16 x 1040 fp8 xs = exp(z-m)*256
#define RMX   160128u   // 16x8 f32 row-max partials (1 KB slot)
#define RSM   161152u   // 16x8 f32 row-sum partials (1 KB slot)
#define LDS_TOTAL 162176

#define WAITVM_(N) asm volatile("s_waitcnt vmcnt(" #N ")" ::: "memory")
#define WAITVM(N) WAITVM_(N)

typedef const __attribute__((address_space(1))) void* gvp;
typedef __attribute__((address_space(3))) void* svp;

__global__ __launch_bounds__(512, 2)
void lstm_fused(const float* __restrict__ x, const float* __restrict__ gum,
                const u8* __restrict__ w1f, const u8* __restrict__ wof,
                const u8* __restrict__ wef, const float* __restrict__ b1,
                const float* __restrict__ b_out, const float* __restrict__ b_emb,
                const float* __restrict__ sos, float* __restrict__ out)
{
    extern __shared__ char smem[];

    const u32 tid = threadIdx.x;
    const u32 w   = tid >> 6;        // wave 0..7
    const u32 l   = tid & 63u;
    const u32 q   = l >> 4;
    const u32 col = l & 15u;
    const int r0  = blockIdx.x << 4;

    const u32 wB  = w << 11;         // wave's 2 KB sub-chunk offset
    const u32 lB  = l << 4;          // l*16 (global load lane offset)
    const u32 l8  = l << 3;          // l*8  (ds read lane offset)
    const u32 q8  = q << 3;
    const u32 colB776  = col * 776u;
    const u32 colB1040 = col * 1040u;

    const char* w1p = (const char*)w1f;
    const char* wop = (const char*)wof;
    const char* wep = (const char*)wef;

// issue one 2 KB wave-chunk (2 x 1 KB linear global_load_lds)
#define ISS(BASE, C) do { u32 _c = (u32)(C); \
    u32 _o = (u32)__builtin_amdgcn_readfirstlane((int)(((_c & 7u) << 14) + wB)); \
    const char* _s = (BASE) + ((size_t)_c << 14) + wB + lB; \
    __builtin_amdgcn_global_load_lds((gvp)_s,          (svp)(smem + _o),          16, 0, 0); \
    __builtin_amdgcn_global_load_lds((gvp)(_s + 1024), (svp)(smem + _o + 1024u),  16, 0, 0); } while (0)

#define CONSA(G, C) { const char* _fb = smem + (((u32)(C) & 7u) << 14) + wB + l8; \
    acc[G][0] = __builtin_amdgcn_mfma_f32_16x16x32_fp8_fp8(a8, *(const i64*)(_fb        ), acc[G][0], 0, 0, 0); \
    acc[G][1] = __builtin_amdgcn_mfma_f32_16x16x32_fp8_fp8(a8, *(const i64*)(_fb +  512u), acc[G][1], 0, 0, 0); \
    acc[G][2] = __builtin_amdgcn_mfma_f32_16x16x32_fp8_fp8(a8, *(const i64*)(_fb + 1024u), acc[G][2], 0, 0, 0); \
    acc[G][3] = __builtin_amdgcn_mfma_f32_16x16x32_fp8_fp8(a8, *(const i64*)(_fb + 1536u), acc[G][3], 0, 0, 0); }

#define CONSB(HF, C) { const char* _fb = smem + (((u32)(C) & 7u) << 14) + wB + l8; \
    accB[HF][0] = __builtin_amdgcn_mfma_f32_16x16x32_fp8_fp8(a8, *(const i64*)(_fb        ), accB[HF][0], 0, 0, 0); \
    accB[HF][1] = __builtin_amdgcn_mfma_f32_16x16x32_fp8_fp8(a8, *(const i64*)(_fb +  512u), accB[HF][1], 0, 0, 0); \
    accB[HF][2] = __builtin_amdgcn_mfma_f32_16x16x32_fp8_fp8(a8, *(const i64*)(_fb + 1024u), accB[HF][2], 0, 0, 0); \
    accB[HF][3] = __builtin_amdgcn_mfma_f32_16x16x32_fp8_fp8(a8, *(const i64*)(_fb + 1536u), accB[HF][3], 0, 0, 0); }

#define CONSC(C) { const char* _fb = smem + (((u32)(C) & 7u) << 14) + wB + l8; \
    i64 _x0 = *(const i64*)(smem + XSO + colB1040 + (((u32)(C)) << 6) + q8); \
    i64 _x1 = *(const i64*)(smem + XSO + colB1040 + (((u32)(C)) << 6) + 32u + q8); \
    accC[0] = __builtin_amdgcn_mfma_f32_16x16x32_fp8_fp8(_x0, *(const i64*)(_fb        ), accC[0], 0, 0, 0); \
    accC[1] = __builtin_amdgcn_mfma_f32_16x16x32_fp8_fp8(_x0, *(const i64*)(_fb +  512u), accC[1], 0, 0, 0); \
    accC[0] = __builtin_amdgcn_mfma_f32_16x16x32_fp8_fp8(_x1, *(const i64*)(_fb + 1024u), accC[0], 0, 0, 0); \
    accC[1] = __builtin_amdgcn_mfma_f32_16x16x32_fp8_fp8(_x1, *(const i64*)(_fb + 1536u), accC[1], 0, 0, 0); }

    // EOS row (nontemporal stream)
    for (u32 i = tid; i < 16 * V_; i += 512) {
        u32 b = i >> 10, v = i & (V_ - 1);
        __builtin_nontemporal_store((v == 0) ? 1.f : 0.f,
                                    &out[((size_t)(r0 + b) * 33 + 32) * V_ + v]);
    }
    // e0 = sos*16 (fp8), h0 = x*16 (fp8)
    for (u32 i = tid; i < 16 * E_; i += 512) {
        u32 b = i >> 8, k = i & (E_ - 1);
        *(u8*)(smem + AEO + b * 776u + k) = f2e4m3(sos[k] * 16.f);
    }
    for (u32 i = tid; i < 16 * H_; i += 512) {
        u32 b = i >> 9, k = i & (H_ - 1);
        *(u8*)(smem + AEO + b * 776u + 256u + k) = f2e4m3(x[(r0 + b) * H_ + k] * 16.f);
    }

    // hoisted biases: wave owns j in [64w, 64w+64)
    float bia[4], bfa[4], bga[4], boa[4];
    #pragma unroll
    for (int jj = 0; jj < 4; ++jj) {
        int j = (w << 6) + (jj << 4) + col;
        bia[jj] = b1[j];           bfa[jj] = b1[H_ + j];
        bga[jj] = b1[2 * H_ + j];  boa[jj] = b1[3 * H_ + j];
    }
    float bov[2][4];
    #pragma unroll
    for (int hf = 0; hf < 2; ++hf)
        #pragma unroll
        for (int jj = 0; jj < 4; ++jj)
            bov[hf][jj] = b_out[(w << 7) + (hf << 6) + (jj << 4) + col];
    float bem16[2];
    #pragma unroll
    for (int jj = 0; jj < 2; ++jj)
        bem16[jj] = b_emb[(w << 5) + (jj << 4) + col] * 16.f;

    float creg[4][4];
    #pragma unroll
    for (int jj = 0; jj < 4; ++jj)
        #pragma unroll
        for (int r = 0; r < 4; ++r) creg[jj][r] = 0.f;

    __syncthreads();

    const f32x4 fz = {0.f, 0.f, 0.f, 0.f};
    const float S1 = 1.f / 1024.f;            // 1/(A_SC*W_SC) = 1/(16*64)

    #pragma unroll 1
    for (int t = 0; t < L_; ++t) {
        // =============== phase A: gates, ring-8 (96 chunks) ===============
        f32x4 acc[4][4];
        #pragma unroll
        for (int g = 0; g < 4; ++g)
            #pragma unroll
            for (int jj = 0; jj < 4; ++jj) acc[g][jj] = fz;

        ISS(w1p, 0); ISS(w1p, 1); ISS(w1p, 2); ISS(w1p, 3);
        ISS(w1p, 4); ISS(w1p, 5); ISS(w1p, 6);
        #pragma unroll 1
        for (int ks = 0; ks < 22; ++ks) {
            i64 a8 = *(const i64*)(smem + AEO + colB776 + ((u32)ks << 5) + q8);
            int c0 = ks << 2;
            #pragma unroll
            for (int g = 0; g < 4; ++g) {
                WAITVM(12);
                CONSA(g, c0 + g);
                ISS(w1p, c0 + g + 7);
            }
        }
        {   // ks=22 (chunks 88..91)
            i64 a8 = *(const i64*)(smem + AEO + colB776 + (22u << 5) + q8);
            WAITVM(12); CONSA(0, 88); ISS(w1p, 95);
            WAITVM(12); CONSA(1, 89);
            WAITVM(10); CONSA(2, 90);
            WAITVM(8);  CONSA(3, 91);
        }
        {   // ks=23 (chunks 92..95)
            i64 a8 = *(const i64*)(smem + AEO + colB776 + (23u << 5) + q8);
            WAITVM(6); CONSA(0, 92);
            WAITVM(4); CONSA(1, 93);
            WAITVM(2); CONSA(2, 94);
            WAITVM(0); CONSA(3, 95);
        }
        __syncthreads();            // all AEO reads done before h overwrite

        #pragma unroll
        for (int jj = 0; jj < 4; ++jj) {
            int j = (w << 6) + (jj << 4) + col;
            #pragma unroll
            for (int r = 0; r < 4; ++r) {
                float gi = sig_(acc[0][jj][r] * S1 + bia[jj]);
                float gf = sig_(acc[1][jj][r] * S1 + bfa[jj]);
                float gg = tanh_(acc[2][jj][r] * S1 + bga[jj]);
                float go = sig_(acc[3][jj][r] * S1 + boa[jj]);
                float c  = gf * creg[jj][r] + gi * gg;
                creg[jj][r] = c;
                float h = go * tanh_(c);
                *(u8*)(smem + AEO + ((q << 2) + r) * 776u + 256u + (u32)j) = f2e4m3(h * 16.f);
            }
        }
        __syncthreads();            // h complete

        // =============== phase B: logits, ring-8 (32 chunks) + softmax ===============
        const float* gt = gum + (size_t)t * (B_ * V_) + (size_t)r0 * V_;
        f32x4 gr[2][4];
        #pragma unroll
        for (int hf = 0; hf < 2; ++hf)
            #pragma unroll
            for (int jj = 0; jj < 4; ++jj) {
                int v = (w << 7) + (hf << 6) + (jj << 4) + col;
                #pragma unroll
                for (int r = 0; r < 4; ++r)
                    gr[hf][jj][r] = __builtin_nontemporal_load(&gt[((q << 2) + r) * V_ + v]);
            }

        f32x4 accB[2][4];
        #pragma unroll
        for (int hf = 0; hf < 2; ++hf)
            #pragma unroll
            for (int jj = 0; jj < 4; ++jj) accB[hf][jj] = fz;

        ISS(wop, 0); ISS(wop, 1); ISS(wop, 2); ISS(wop, 3);
        ISS(wop, 4); ISS(wop, 5); ISS(wop, 6);
        #pragma unroll 1
        for (int ks = 0; ks < 12; ++ks) {
            i64 a8 = *(const i64*)(smem + AEO + colB776 + 256u + ((u32)ks << 5) + q8);
            int c0 = ks << 1;
            WAITVM(12); CONSB(0, c0);     ISS(wop, c0 + 7);
            WAITVM(12); CONSB(1, c0 + 1); ISS(wop, c0 + 8);
        }
        {   // ks=12 (chunks 24,25)
            i64 a8 = *(const i64*)(smem + AEO + colB776 + 256u + (12u << 5) + q8);
            WAITVM(12); CONSB(0, 24); ISS(wop, 31);
            WAITVM(12); CONSB(1, 25);
        }
        {   i64 a8 = *(const i64*)(smem + AEO + colB776 + 256u + (13u << 5) + q8);
            WAITVM(10); CONSB(0, 26);
            WAITVM(8);  CONSB(1, 27);
        }
        {   i64 a8 = *(const i64*)(smem + AEO + colB776 + 256u + (14u << 5) + q8);
            WAITVM(6); CONSB(0, 28);
            WAITVM(4); CONSB(1, 29);
        }
        {   i64 a8 = *(const i64*)(smem + AEO + colB776 + 256u + (15u << 5) + q8);
            WAITVM(2); CONSB(0, 30);
            WAITVM(0); CONSB(1, 31);
        }

        // z = acc*S1 + bias + gumbel (in place); row-max
        float mx[4];
        #pragma unroll
        for (int r = 0; r < 4; ++r) mx[r] = -1e30f;
        #pragma unroll
        for (int hf = 0; hf < 2; ++hf)
            #pragma unroll
            for (int jj = 0; jj < 4; ++jj)
                #pragma unroll
                for (int r = 0; r < 4; ++r) {
                    float zz = accB[hf][jj][r] * S1 + bov[hf][jj] + gr[hf][jj][r];
                    accB[hf][jj][r] = zz;
                    mx[r] = fmaxf(mx[r], zz);
                }
        #pragma unroll
        for (int m = 1; m < 16; m <<= 1)
            #pragma unroll
            for (int r = 0; r < 4; ++r) mx[r] = fmaxf(mx[r], __shfl_xor(mx[r], m, 64));
        if (col == 0) {
            #pragma unroll
            for (int r = 0; r < 4; ++r)
                *(float*)(smem + RMX + ((((q << 2) + r) << 3) + w) * 4u) = mx[r];
        }
        __syncthreads();
        float m_[4];
        #pragma unroll
        for (int r = 0; r < 4; ++r) {
            float mm = -1e30f;
            #pragma unroll
            for (int ww = 0; ww < 8; ++ww)
                mm = fmaxf(mm, *(const float*)(smem + RMX + ((((q << 2) + r) << 3) + ww) * 4u));
            m_[r] = mm;
        }
        // eb = exp(z - m) in place; row-sum; stage xs = eb*256 fp8
        float ps[4] = {0.f, 0.f, 0.f, 0.f};
        #pragma unroll
        for (int hf = 0; hf < 2; ++hf)
            #pragma unroll
            for (int jj = 0; jj < 4; ++jj) {
                u32 v = (w << 7) + (hf << 6) + (jj << 4) + col;
                #pragma unroll
                for (int r = 0; r < 4; ++r) {
                    float Ee = __expf(accB[hf][jj][r] - m_[r]);
                    accB[hf][jj][r] = Ee;
                    ps[r] += Ee;
                    *(u8*)(smem + XSO + ((q << 2) + r) * 1040u + v) = f2e4m3(Ee * 256.f);
                }
            }
        #pragma unroll
        for (int m = 1; m < 16; m <<= 1)
            #pragma unroll
            for (int r = 0; r < 4; ++r) ps[r] += __shfl_xor(ps[r], m, 64);
        if (col == 0) {
            #pragma unroll
            for (int r = 0; r < 4; ++r)
                *(float*)(smem + RSM + ((((q << 2) + r) << 3) + w) * 4u) = ps[r];
        }
        __syncthreads();
        float invs[4];
        #pragma unroll
        for (int r = 0; r < 4; ++r) {
            float s = 0.f;
            #pragma unroll
            for (int ww = 0; ww < 8; ++ww)
                s += *(const float*)(smem + RSM + ((((q << 2) + r) << 3) + ww) * 4u);
            invs[r] = 1.f / s;
        }
        // normalized softmax out (fp32, nontemporal stream)
        #pragma unroll
        for (int hf = 0; hf < 2; ++hf)
            #pragma unroll
            for (int jj = 0; jj < 4; ++jj) {
                int v = (w << 7) + (hf << 6) + (jj << 4) + col;
                #pragma unroll
                for (int r = 0; r < 4; ++r) {
                    int b = (q << 2) + r;
                    __builtin_nontemporal_store(accB[hf][jj][r] * invs[r],
                        &out[((size_t)(r0 + b) * 33 + t) * V_ + v]);
                }
            }

        // =============== phase C: e_new, ring-8 (16 chunks) ===============
        f32x4 accC[2];
        accC[0] = fz; accC[1] = fz;
        ISS(wep, 0); ISS(wep, 1); ISS(wep, 2); ISS(wep, 3);
        ISS(wep, 4); ISS(wep, 5); ISS(wep, 6);
        #pragma unroll 1
        for (int c2 = 0; c2 < 9; ++c2) {
            WAITVM(12);
            CONSC(c2);
            ISS(wep, c2 + 7);
        }
        WAITVM(12); CONSC(9);
        WAITVM(10); CONSC(10);
        WAITVM(8);  CONSC(11);
        WAITVM(6);  CONSC(12);
        WAITVM(4);  CONSC(13);
        WAITVM(2);  CONSC(14);
        WAITVM(0);  CONSC(15);

        {   // e = accC*invs/(256*64) + b_emb ; store e*16 as fp8
            #pragma unroll
            for (int jj = 0; jj < 2; ++jj) {
                u32 ce = (w << 5) + (jj << 4) + col;
                #pragma unroll
                for (int r = 0; r < 4; ++r) {
                    float e_ = accC[jj][r] * invs[r] * (16.f / 16384.f) + bem16[jj];
                    *(u8*)(smem + AEO + ((q << 2) + r) * 776u + ce) = f2e4m3(e_);
                }
            }
        }
        __syncthreads();            // e complete before next step's phase A
    }
#undef ISS
#undef CONSA
#undef CONSB
#undef CONSC
}

extern "C" void kernel_launch(void* const* d_in, const int* in_sizes, int n_in,
                              void* d_out, int out_size, void* d_ws, size_t ws_size,
                              hipStream_t stream) {
    const float* x     = (const float*)d_in[0];
    const float* gum   = (const float*)d_in[1];
    const float* W_ih  = (const float*)d_in[2];
    const float* W_hh  = (const float*)d_in[3];
    const float* b_ih  = (const float*)d_in[4];
    const float* b_hh  = (const float*)d_in[5];
    const float* W_out = (const float*)d_in[6];
    const float* b_out = (const float*)d_in[7];
    const float* W_emb = (const float*)d_in[8];
    const float* b_emb = (const float*)d_in[9];
    const float* sos   = (const float*)d_in[10];
    float* out = (float*)d_out;

    char* ws = (char*)d_ws;
    u8*    w1f = (u8*)(ws);                    // 1,572,864 B (fp8)
    u8*    wof = (u8*)(ws + 1572864);          //   524,288 B (fp8)
    u8*    wef = (u8*)(ws + 2097152);          //   262,144 B (fp8)
    float* b1  = (float*)(ws + 2359296);       //     8,192 B

    hipFuncSetAttribute((const void*)lstm_fused,
                        hipFuncAttributeMaxDynamicSharedMemorySize, LDS_TOTAL);

    prep<<<9224, 256, 0, stream>>>(W_ih, W_hh, b_ih, b_hh, W_out, W_emb,
                                   w1f, wof, wef, b1);
    lstm_fused<<<128, 512, LDS_TOTAL, stream>>>(x, gum, w1f, wof, wef, b1,
                                                b_out, b_emb, sos, out);
}